// Round 7
// baseline (23285.437 us; speedup 1.0000x reference)
//
#include <hip/hip_runtime.h>
#include <hip/hip_bf16.h>

#define T_LEN 2048
#define N_IN 256
#define N_H 512
#define N_B 64
#define N_WG 32
#define FLAG_STRIDE 32  // ints -> 128B per flag line

typedef float f32x4 __attribute__((ext_vector_type(4)));
typedef __bf16 bf16x8 __attribute__((ext_vector_type(8)));

__device__ __forceinline__ unsigned short f2bf(float f) {
  union { float f; unsigned int i; } x; x.f = f;
  unsigned int r = x.i + 0x7fffu + ((x.i >> 16) & 1u);  // RNE
  return (unsigned short)(r >> 16);
}
__device__ __forceinline__ float sigm(float x) { return 1.0f / (1.0f + __expf(-x)); }
__device__ __forceinline__ float tanh_(float x) {
  float a = fabsf(x);
  float e = __expf(2.0f * a);
  float r = 1.0f - 2.0f / (e + 1.0f);
  return copysignf(r, x);
}
// convert 8 consecutive f32 -> bf16x8 (RNE)
__device__ __forceinline__ bf16x8 cvt8(const float* __restrict__ p) {
  f32x4 a = *(const f32x4*)(const void*)p;
  f32x4 b = *(const f32x4*)(const void*)(p + 4);
  union { bf16x8 v; unsigned short u[8]; } r;
  #pragma unroll
  for (int j = 0; j < 4; ++j) { r.u[j] = f2bf(a[j]); r.u[j + 4] = f2bf(b[j]); }
  return r.v;
}

// ws layout: [0,4096) flags (32 x FLAG_STRIDE ints), [4096, 4096+131072) hbuf (2 x 64 x 512 bf16)
__global__ void lstm_init(int* __restrict__ ws) {
  int i = blockIdx.x * 256 + threadIdx.x;  // grid 132 -> 33792 ints = 4096B + 128KB
  if (i < (4096 + 2 * N_B * N_H * 2) / 4) ws[i] = 0;
}

__global__ __launch_bounds__(256, 1) void lstm_persist(
    const float* __restrict__ X,     // [64, 2048, 256] f32
    const float* __restrict__ HID,   // [1, 512] f32 (passthrough)
    const float* __restrict__ Wi, const float* __restrict__ bi,
    const float* __restrict__ Wg, const float* __restrict__ bg,
    const float* __restrict__ Wo, const float* __restrict__ bo,
    const float* __restrict__ Wout, const float* __restrict__ bout,
    float* __restrict__ out,                  // f32: [64*256] + [512]
    unsigned short* __restrict__ hbuf,        // 2 x 64 x 512 bf16 (double buffer)
    int* __restrict__ flags)                  // 32 x FLAG_STRIDE ints
{
  extern __shared__ unsigned short ldsw[];  // 48 rows x 768 k, swizzled, 73728 B
  const int tid = threadIdx.x;
  const int wg = blockIdx.x;       // 0..31 -> column slice jb..jb+15
  const int lane = tid & 63;
  const int wave = tid >> 6;       // 0..3 -> M-tile (rows 16*wave..)
  const int q = lane >> 4;         // 0..3
  const int c = lane & 15;
  const int jb = wg * 16;

  // hidden passthrough output (independent of recurrence), f32
  if (wg == N_WG - 1) {
    for (int i = tid; i < N_H; i += 256) out[N_B * N_IN + i] = HID[i];
  }

  // ---- stage weight slice into LDS (f32 -> bf16), transposed: Wt[r][k], r = gate*16 + (col-jb) ----
  for (int idx = tid; idx < 48 * 768; idx += 256) {
    int k = idx / 48;
    int r = idx - k * 48;
    int g = r >> 4;
    int cc = r & 15;
    const float* W = (g == 0) ? Wi : ((g == 1) ? Wg : Wo);
    unsigned short v = f2bf(W[k * N_H + jb + cc]);
    int byte = (r * 1536 + k * 2) ^ ((r & 7) << 4);  // XOR swizzle (G4)
    *(unsigned short*)((char*)ldsw + byte) = v;
  }
  __syncthreads();

  // B-fragment read: lane holds Wt[gate*16 + c][kk*32 + q*8 + j], j=0..7 (16B contiguous)
  auto ldb = [&](int g, int kk) -> bf16x8 {
    int r = g * 16 + c;
    int byte = (r * 1536 + kk * 64 + q * 16) ^ ((r & 7) << 4);
    return *(const bf16x8*)((const char*)ldsw + byte);
  };

  const float Bi = bi[jb + c];
  const float Bg = bg[jb + c];
  const float Bo = bo[jb + c];

  const int rb = wave * 16 + c;  // batch row for A-fragments
  const float* xrow = X + (size_t)rb * (T_LEN * N_IN);

  #pragma unroll 1
  for (int t = 0; t < T_LEN; ++t) {
    f32x4 ai = {0.f, 0.f, 0.f, 0.f};
    f32x4 ag = {0.f, 0.f, 0.f, 0.f};
    f32x4 ao = {0.f, 0.f, 0.f, 0.f};

    // ---- x-part GEMM (independent of h -> before the flag wait) ----
    const float* xp = xrow + (size_t)t * N_IN + q * 8;
    #pragma unroll
    for (int kk = 0; kk < 8; ++kk) {
      bf16x8 a = cvt8(xp + kk * 32);
      ai = __builtin_amdgcn_mfma_f32_16x16x32_bf16(a, ldb(0, kk), ai, 0, 0, 0);
      ag = __builtin_amdgcn_mfma_f32_16x16x32_bf16(a, ldb(1, kk), ag, 0, 0, 0);
      ao = __builtin_amdgcn_mfma_f32_16x16x32_bf16(a, ldb(2, kk), ao, 0, 0, 0);
    }

    // ---- wait until all WGs published h_t ----
    if (wave == 0) {
      for (;;) {
        int v = __hip_atomic_load(&flags[(lane & 31) * FLAG_STRIDE],
                                  __ATOMIC_ACQUIRE, __HIP_MEMORY_SCOPE_AGENT);
        if (__all(v >= t)) break;
      }
    }
    __syncthreads();
    __threadfence();

    // ---- h-part GEMM: load h_t fragments via agent-scope atomic u64 loads (cache-coherent) ----
    const unsigned long long* hq =
        (const unsigned long long*)(hbuf + (size_t)(t & 1) * (N_B * N_H)) + rb * 128 + q * 2;
    unsigned long long hreg[32];
    #pragma unroll
    for (int kk = 0; kk < 16; ++kk) {
      hreg[2 * kk]     = __hip_atomic_load(hq + kk * 8,     __ATOMIC_RELAXED, __HIP_MEMORY_SCOPE_AGENT);
      hreg[2 * kk + 1] = __hip_atomic_load(hq + kk * 8 + 1, __ATOMIC_RELAXED, __HIP_MEMORY_SCOPE_AGENT);
    }
    #pragma unroll
    for (int kk = 0; kk < 16; ++kk) {
      union { unsigned long long u[2]; bf16x8 v; } a;
      a.u[0] = hreg[2 * kk]; a.u[1] = hreg[2 * kk + 1];
      ai = __builtin_amdgcn_mfma_f32_16x16x32_bf16(a.v, ldb(0, kk + 8), ai, 0, 0, 0);
      ag = __builtin_amdgcn_mfma_f32_16x16x32_bf16(a.v, ldb(1, kk + 8), ag, 0, 0, 0);
      ao = __builtin_amdgcn_mfma_f32_16x16x32_bf16(a.v, ldb(2, kk + 8), ao, 0, 0, 0);
    }

    // ---- nonlinearity + write h_{t+1} slice via agent-scope atomic u16 stores ----
    unsigned short* hn = hbuf + (size_t)((t + 1) & 1) * (N_B * N_H);
    #pragma unroll
    for (int j = 0; j < 4; ++j) {
      float iv = sigm(ai[j] + Bi);
      float gv = tanh_(ag[j] + Bg);
      float ov = sigm(ao[j] + Bo);
      float h = ov * tanh_(iv * gv);
      int row = wave * 16 + q * 4 + j;  // D layout: col=lane&15, row=q*4+j (m89)
      __hip_atomic_store(&hn[row * N_H + jb + c], f2bf(h),
                         __ATOMIC_RELAXED, __HIP_MEMORY_SCOPE_AGENT);
    }

    __threadfence();  // data visible before flag release
    __syncthreads();
    if (tid == 0)
      __hip_atomic_store(&flags[wg * FLAG_STRIDE], t + 1,
                         __ATOMIC_RELEASE, __HIP_MEMORY_SCOPE_AGENT);
  }

  // ---- epilogue: output = h_T @ W_out + b_out (f32 out); h_T is in hbuf[0] (T even) ----
  if (wg < 16) {
    if (wave == 0) {
      for (;;) {
        int v = __hip_atomic_load(&flags[(lane & 31) * FLAG_STRIDE],
                                  __ATOMIC_ACQUIRE, __HIP_MEMORY_SCOPE_AGENT);
        if (__all(v >= T_LEN)) break;
      }
    }
    __syncthreads();
    __threadfence();

    const unsigned long long* hq0 = (const unsigned long long*)hbuf + rb * 128 + q * 2;
    f32x4 acc = {0.f, 0.f, 0.f, 0.f};
    #pragma unroll 4
    for (int kk = 0; kk < 16; ++kk) {
      union { unsigned long long u[2]; bf16x8 v; } a;
      a.u[0] = __hip_atomic_load(hq0 + kk * 8,     __ATOMIC_RELAXED, __HIP_MEMORY_SCOPE_AGENT);
      a.u[1] = __hip_atomic_load(hq0 + kk * 8 + 1, __ATOMIC_RELAXED, __HIP_MEMORY_SCOPE_AGENT);
      union { bf16x8 v; unsigned short u[8]; } bb;
      #pragma unroll
      for (int j = 0; j < 8; ++j)
        bb.u[j] = f2bf(Wout[(size_t)(kk * 32 + q * 8 + j) * N_IN + jb + c]);
      acc = __builtin_amdgcn_mfma_f32_16x16x32_bf16(a.v, bb.v, acc, 0, 0, 0);
    }
    const float Bb = bout[jb + c];
    #pragma unroll
    for (int j = 0; j < 4; ++j) {
      int row = wave * 16 + q * 4 + j;
      out[row * N_IN + jb + c] = acc[j] + Bb;  // f32 store
    }
  }
}

extern "C" void kernel_launch(void* const* d_in, const int* in_sizes, int n_in,
                              void* d_out, int out_size, void* d_ws, size_t ws_size,
                              hipStream_t stream) {
  const float* X    = (const float*)d_in[0];
  const float* HID  = (const float*)d_in[1];
  const float* Wi   = (const float*)d_in[2];
  const float* bi   = (const float*)d_in[3];
  const float* Wg   = (const float*)d_in[4];
  const float* bg   = (const float*)d_in[5];
  const float* Wo   = (const float*)d_in[6];
  const float* bo   = (const float*)d_in[7];
  const float* Wout = (const float*)d_in[8];
  const float* bout = (const float*)d_in[9];

  int* flags = (int*)d_ws;
  unsigned short* hbuf = (unsigned short*)((char*)d_ws + 4096);

  lstm_init<<<dim3(132), dim3(256), 0, stream>>>((int*)d_ws);
  lstm_persist<<<dim3(N_WG), dim3(256), 48 * 768 * 2, stream>>>(
      X, HID, Wi, bi, Wg, bg, Wo, bo, Wout, bout,
      (float*)d_out, hbuf, flags);
}

// Round 8
// 19590.973 us; speedup vs baseline: 1.1886x; 1.1886x over previous
//
#include <hip/hip_runtime.h>
#include <hip/hip_bf16.h>

#define T_LEN 2048
#define N_IN 256
#define N_H 512
#define N_B 64
#define N_WG 32
#define FLAG_STRIDE 32  // ints -> 128B per flag line

typedef float f32x4 __attribute__((ext_vector_type(4)));
typedef __bf16 bf16x8 __attribute__((ext_vector_type(8)));

__device__ __forceinline__ unsigned short f2bf(float f) {
  union { float f; unsigned int i; } x; x.f = f;
  unsigned int r = x.i + 0x7fffu + ((x.i >> 16) & 1u);  // RNE
  return (unsigned short)(r >> 16);
}
__device__ __forceinline__ float sigm(float x) { return 1.0f / (1.0f + __expf(-x)); }
__device__ __forceinline__ float tanh_(float x) {
  float a = fabsf(x);
  float e = __expf(2.0f * a);
  float r = 1.0f - 2.0f / (e + 1.0f);
  return copysignf(r, x);
}
// convert 8 consecutive f32 -> bf16x8 (RNE)
__device__ __forceinline__ bf16x8 cvt8(const float* __restrict__ p) {
  f32x4 a = *(const f32x4*)(const void*)p;
  f32x4 b = *(const f32x4*)(const void*)(p + 4);
  union { bf16x8 v; unsigned short u[8]; } r;
  #pragma unroll
  for (int j = 0; j < 4; ++j) { r.u[j] = f2bf(a[j]); r.u[j + 4] = f2bf(b[j]); }
  return r.v;
}

// ws layout: [0,4096) flags (32 x FLAG_STRIDE ints), [4096, 4096+131072) hbuf (2 x 64 x 512 bf16)
__global__ void lstm_init(int* __restrict__ ws) {
  int i = blockIdx.x * 256 + threadIdx.x;  // grid 132 -> 33792 ints = 4096B + 128KB
  if (i < (4096 + 2 * N_B * N_H * 2) / 4) ws[i] = 0;
}

__global__ __launch_bounds__(256, 1) void lstm_persist(
    const float* __restrict__ X,     // [64, 2048, 256] f32
    const float* __restrict__ HID,   // [1, 512] f32 (passthrough)
    const float* __restrict__ Wi, const float* __restrict__ bi,
    const float* __restrict__ Wg, const float* __restrict__ bg,
    const float* __restrict__ Wo, const float* __restrict__ bo,
    const float* __restrict__ Wout, const float* __restrict__ bout,
    float* __restrict__ out,                  // f32: [64*256] + [512]
    unsigned short* __restrict__ hbuf,        // 2 x 64 x 512 bf16 (double buffer)
    int* __restrict__ flags)                  // 32 x FLAG_STRIDE ints
{
  extern __shared__ unsigned short ldsw[];  // 48 rows x 768 k, swizzled, 73728 B
  const int tid = threadIdx.x;
  const int wg = blockIdx.x;       // 0..31 -> column slice jb..jb+15
  const int lane = tid & 63;
  const int wave = tid >> 6;       // 0..3 -> M-tile (rows 16*wave..)
  const int q = lane >> 4;         // 0..3
  const int c = lane & 15;
  const int jb = wg * 16;

  // hidden passthrough output (independent of recurrence), f32
  if (wg == N_WG - 1) {
    for (int i = tid; i < N_H; i += 256) out[N_B * N_IN + i] = HID[i];
  }

  // ---- stage weight slice into LDS (f32 -> bf16), transposed: Wt[r][k], r = gate*16 + (col-jb) ----
  for (int idx = tid; idx < 48 * 768; idx += 256) {
    int k = idx / 48;
    int r = idx - k * 48;
    int g = r >> 4;
    int cc = r & 15;
    const float* W = (g == 0) ? Wi : ((g == 1) ? Wg : Wo);
    unsigned short v = f2bf(W[k * N_H + jb + cc]);
    int byte = (r * 1536 + k * 2) ^ ((r & 7) << 4);  // XOR swizzle (G4)
    *(unsigned short*)((char*)ldsw + byte) = v;
  }
  __syncthreads();

  // B-fragment read: lane holds Wt[gate*16 + c][kk*32 + q*8 + j], j=0..7 (16B contiguous)
  auto ldb = [&](int g, int kk) -> bf16x8 {
    int r = g * 16 + c;
    int byte = (r * 1536 + kk * 64 + q * 16) ^ ((r & 7) << 4);
    return *(const bf16x8*)((const char*)ldsw + byte);
  };

  const float Bi = bi[jb + c];
  const float Bg = bg[jb + c];
  const float Bo = bo[jb + c];

  const int rb = wave * 16 + c;  // batch row for A-fragments
  const float* xrow = X + (size_t)rb * (T_LEN * N_IN);

  #pragma unroll 1
  for (int t = 0; t < T_LEN; ++t) {
    f32x4 ai = {0.f, 0.f, 0.f, 0.f};
    f32x4 ag = {0.f, 0.f, 0.f, 0.f};
    f32x4 ao = {0.f, 0.f, 0.f, 0.f};

    // ---- x-part GEMM (independent of h -> before the flag wait) ----
    const float* xp = xrow + (size_t)t * N_IN + q * 8;
    #pragma unroll
    for (int kk = 0; kk < 8; ++kk) {
      bf16x8 a = cvt8(xp + kk * 32);
      ai = __builtin_amdgcn_mfma_f32_16x16x32_bf16(a, ldb(0, kk), ai, 0, 0, 0);
      ag = __builtin_amdgcn_mfma_f32_16x16x32_bf16(a, ldb(1, kk), ag, 0, 0, 0);
      ao = __builtin_amdgcn_mfma_f32_16x16x32_bf16(a, ldb(2, kk), ao, 0, 0, 0);
    }

    // ---- wait until all WGs published h_t (RELAXED poll; one acquire fence after) ----
    if (wave == 0) {
      for (;;) {
        int v = __hip_atomic_load(&flags[(lane & 31) * FLAG_STRIDE],
                                  __ATOMIC_RELAXED, __HIP_MEMORY_SCOPE_AGENT);
        if (__all(v >= t)) break;
      }
    }
    __syncthreads();
    __builtin_amdgcn_fence(__ATOMIC_ACQUIRE, "agent");  // single buffer_inv per step

    // ---- h-part GEMM: load h_t fragments via agent-scope atomic u64 loads (coherent) ----
    const unsigned long long* hq =
        (const unsigned long long*)(hbuf + (size_t)(t & 1) * (N_B * N_H)) + rb * 128 + q * 2;
    unsigned long long hreg[32];
    #pragma unroll
    for (int kk = 0; kk < 16; ++kk) {
      hreg[2 * kk]     = __hip_atomic_load(hq + kk * 8,     __ATOMIC_RELAXED, __HIP_MEMORY_SCOPE_AGENT);
      hreg[2 * kk + 1] = __hip_atomic_load(hq + kk * 8 + 1, __ATOMIC_RELAXED, __HIP_MEMORY_SCOPE_AGENT);
    }
    #pragma unroll
    for (int kk = 0; kk < 16; ++kk) {
      union { unsigned long long u[2]; bf16x8 v; } a;
      a.u[0] = hreg[2 * kk]; a.u[1] = hreg[2 * kk + 1];
      ai = __builtin_amdgcn_mfma_f32_16x16x32_bf16(a.v, ldb(0, kk + 8), ai, 0, 0, 0);
      ag = __builtin_amdgcn_mfma_f32_16x16x32_bf16(a.v, ldb(1, kk + 8), ag, 0, 0, 0);
      ao = __builtin_amdgcn_mfma_f32_16x16x32_bf16(a.v, ldb(2, kk + 8), ao, 0, 0, 0);
    }

    // ---- nonlinearity + write h_{t+1} slice via agent-scope atomic u16 stores ----
    unsigned short* hn = hbuf + (size_t)((t + 1) & 1) * (N_B * N_H);
    #pragma unroll
    for (int j = 0; j < 4; ++j) {
      float iv = sigm(ai[j] + Bi);
      float gv = tanh_(ag[j] + Bg);
      float ov = sigm(ao[j] + Bo);
      float h = ov * tanh_(iv * gv);
      int row = wave * 16 + q * 4 + j;  // D layout: col=lane&15, row=q*4+j (m89)
      __hip_atomic_store(&hn[row * N_H + jb + c], f2bf(h),
                         __ATOMIC_RELAXED, __HIP_MEMORY_SCOPE_AGENT);
    }

    __syncthreads();  // drains each thread's stores (vmcnt0) before flag release
    if (tid == 0)
      __hip_atomic_store(&flags[wg * FLAG_STRIDE], t + 1,
                         __ATOMIC_RELEASE, __HIP_MEMORY_SCOPE_AGENT);
  }

  // ---- epilogue: output = h_T @ W_out + b_out (f32 out); h_T is in hbuf[0] (T even) ----
  if (wg < 16) {
    if (wave == 0) {
      for (;;) {
        int v = __hip_atomic_load(&flags[(lane & 31) * FLAG_STRIDE],
                                  __ATOMIC_RELAXED, __HIP_MEMORY_SCOPE_AGENT);
        if (__all(v >= T_LEN)) break;
      }
    }
    __syncthreads();
    __builtin_amdgcn_fence(__ATOMIC_ACQUIRE, "agent");

    const unsigned long long* hq0 = (const unsigned long long*)hbuf + rb * 128 + q * 2;
    f32x4 acc = {0.f, 0.f, 0.f, 0.f};
    #pragma unroll 4
    for (int kk = 0; kk < 16; ++kk) {
      union { unsigned long long u[2]; bf16x8 v; } a;
      a.u[0] = __hip_atomic_load(hq0 + kk * 8,     __ATOMIC_RELAXED, __HIP_MEMORY_SCOPE_AGENT);
      a.u[1] = __hip_atomic_load(hq0 + kk * 8 + 1, __ATOMIC_RELAXED, __HIP_MEMORY_SCOPE_AGENT);
      union { bf16x8 v; unsigned short u[8]; } bb;
      #pragma unroll
      for (int j = 0; j < 8; ++j)
        bb.u[j] = f2bf(Wout[(size_t)(kk * 32 + q * 8 + j) * N_IN + jb + c]);
      acc = __builtin_amdgcn_mfma_f32_16x16x32_bf16(a.v, bb.v, acc, 0, 0, 0);
    }
    const float Bb = bout[jb + c];
    #pragma unroll
    for (int j = 0; j < 4; ++j) {
      int row = wave * 16 + q * 4 + j;
      out[row * N_IN + jb + c] = acc[j] + Bb;  // f32 store
    }
  }
}

extern "C" void kernel_launch(void* const* d_in, const int* in_sizes, int n_in,
                              void* d_out, int out_size, void* d_ws, size_t ws_size,
                              hipStream_t stream) {
  const float* X    = (const float*)d_in[0];
  const float* HID  = (const float*)d_in[1];
  const float* Wi   = (const float*)d_in[2];
  const float* bi   = (const float*)d_in[3];
  const float* Wg   = (const float*)d_in[4];
  const float* bg   = (const float*)d_in[5];
  const float* Wo   = (const float*)d_in[6];
  const float* bo   = (const float*)d_in[7];
  const float* Wout = (const float*)d_in[8];
  const float* bout = (const float*)d_in[9];

  int* flags = (int*)d_ws;
  unsigned short* hbuf = (unsigned short*)((char*)d_ws + 4096);

  lstm_init<<<dim3(132), dim3(256), 0, stream>>>((int*)d_ws);
  lstm_persist<<<dim3(N_WG), dim3(256), 48 * 768 * 2, stream>>>(
      X, HID, Wi, bi, Wg, bg, Wo, bo, Wout, bout,
      (float*)d_out, hbuf, flags);
}

// Round 9
// 16843.739 us; speedup vs baseline: 1.3824x; 1.1631x over previous
//
#include <hip/hip_runtime.h>
#include <hip/hip_bf16.h>

#define T_LEN 2048
#define N_IN 256
#define N_H 512
#define N_B 64
#define N_WG 32
#define FLAG_STRIDE 32  // ints -> 128B per flag line

typedef float f32x4 __attribute__((ext_vector_type(4)));
typedef __bf16 bf16x8 __attribute__((ext_vector_type(8)));

__device__ __forceinline__ unsigned short f2bf(float f) {
  union { float f; unsigned int i; } x; x.f = f;
  unsigned int r = x.i + 0x7fffu + ((x.i >> 16) & 1u);  // RNE
  return (unsigned short)(r >> 16);
}
__device__ __forceinline__ float sigm(float x) { return 1.0f / (1.0f + __expf(-x)); }
__device__ __forceinline__ float tanh_(float x) {
  float a = fabsf(x);
  float e = __expf(2.0f * a);
  float r = 1.0f - 2.0f / (e + 1.0f);
  return copysignf(r, x);
}
// convert 8 consecutive f32 -> bf16x8 (RNE)
__device__ __forceinline__ bf16x8 cvt8(const float* __restrict__ p) {
  f32x4 a = *(const f32x4*)(const void*)p;
  f32x4 b = *(const f32x4*)(const void*)(p + 4);
  union { bf16x8 v; unsigned short u[8]; } r;
  #pragma unroll
  for (int j = 0; j < 4; ++j) { r.u[j] = f2bf(a[j]); r.u[j + 4] = f2bf(b[j]); }
  return r.v;
}

// ws layout: [0,4096) flags (32 x FLAG_STRIDE ints),
//            [4096, 4096+131072) hbuf: 2 bufs x 32 wg-slices x 64 rows x 16 cols (bf16)
__global__ void lstm_init(int* __restrict__ ws) {
  int i = blockIdx.x * 256 + threadIdx.x;  // grid 132 covers 4096B + 128KB
  if (i < (4096 + 2 * N_B * N_H * 2) / 4) ws[i] = 0;
}

__global__ __launch_bounds__(256, 1) void lstm_persist(
    const float* __restrict__ X,     // [64, 2048, 256] f32
    const float* __restrict__ HID,   // [1, 512] f32 (passthrough)
    const float* __restrict__ Wi, const float* __restrict__ bi,
    const float* __restrict__ Wg, const float* __restrict__ bg,
    const float* __restrict__ Wo, const float* __restrict__ bo,
    const float* __restrict__ Wout, const float* __restrict__ bout,
    float* __restrict__ out,                  // f32: [64*256] + [512]
    unsigned short* __restrict__ hbuf,        // see layout above
    int* __restrict__ flags)                  // 32 x FLAG_STRIDE ints
{
  extern __shared__ unsigned short ldsw[];  // 48 rows x 768 k, swizzled, 73728 B
  const int tid = threadIdx.x;
  const int wg = blockIdx.x;       // 0..31 -> column slice jb..jb+15
  const int lane = tid & 63;
  const int wave = tid >> 6;       // 0..3 -> M-tile (rows 16*wave..)
  const int q = lane >> 4;         // 0..3
  const int c = lane & 15;
  const int jb = wg * 16;

  // hidden passthrough output (independent of recurrence), f32
  if (wg == N_WG - 1) {
    for (int i = tid; i < N_H; i += 256) out[N_B * N_IN + i] = HID[i];
  }

  // ---- stage weight slice into LDS (f32 -> bf16), transposed: Wt[r][k], r = gate*16 + (col-jb) ----
  for (int idx = tid; idx < 48 * 768; idx += 256) {
    int k = idx / 48;
    int r = idx - k * 48;
    int g = r >> 4;
    int cc = r & 15;
    const float* W = (g == 0) ? Wi : ((g == 1) ? Wg : Wo);
    unsigned short v = f2bf(W[k * N_H + jb + cc]);
    int byte = (r * 1536 + k * 2) ^ ((r & 7) << 4);  // XOR swizzle (G4)
    *(unsigned short*)((char*)ldsw + byte) = v;
  }
  __syncthreads();

  // B-fragment read: lane holds Wt[gate*16 + c][kk*32 + q*8 + j], j=0..7 (16B contiguous)
  auto ldb = [&](int g, int kk) -> bf16x8 {
    int r = g * 16 + c;
    int byte = (r * 1536 + kk * 64 + q * 16) ^ ((r & 7) << 4);
    return *(const bf16x8*)((const char*)ldsw + byte);
  };

  const float Bi = bi[jb + c];
  const float Bg = bg[jb + c];
  const float Bo = bo[jb + c];

  const int rb = wave * 16 + c;  // batch row for A-fragments
  const float* xrow = X + (size_t)rb * (T_LEN * N_IN);

  // h fragment address helper: element (row rb, col k) of buffer buf:
  //   hbuf[buf*32768 + (k>>4)*1024 + rb*16 + (k&15)]
  #pragma unroll 1
  for (int t = 0; t < T_LEN; ++t) {
    f32x4 ai = {0.f, 0.f, 0.f, 0.f};
    f32x4 ag = {0.f, 0.f, 0.f, 0.f};
    f32x4 ao = {0.f, 0.f, 0.f, 0.f};

    // ---- x-part GEMM (independent of h -> before the flag wait) ----
    const float* xp = xrow + (size_t)t * N_IN + q * 8;
    #pragma unroll
    for (int kk = 0; kk < 8; ++kk) {
      bf16x8 a = cvt8(xp + kk * 32);
      ai = __builtin_amdgcn_mfma_f32_16x16x32_bf16(a, ldb(0, kk), ai, 0, 0, 0);
      ag = __builtin_amdgcn_mfma_f32_16x16x32_bf16(a, ldb(1, kk), ag, 0, 0, 0);
      ao = __builtin_amdgcn_mfma_f32_16x16x32_bf16(a, ldb(2, kk), ao, 0, 0, 0);
    }

    // ---- wait until all WGs published h_t (RELAXED poll; one acquire fence after) ----
    if (wave == 0) {
      for (;;) {
        int v = __hip_atomic_load(&flags[(lane & 31) * FLAG_STRIDE],
                                  __ATOMIC_RELAXED, __HIP_MEMORY_SCOPE_AGENT);
        if (__all(v >= t)) break;
      }
    }
    __syncthreads();
    __builtin_amdgcn_fence(__ATOMIC_ACQUIRE, "agent");  // inv L1/L2 once per step

    // ---- h-part GEMM: plain vectorized loads (coherent after the inv) ----
    const unsigned short* hb = hbuf + (size_t)(t & 1) * (N_B * N_H) + rb * 16;
    bf16x8 hfrag[16];
    #pragma unroll
    for (int kk = 0; kk < 16; ++kk) {
      int k0 = kk * 32 + q * 8;
      hfrag[kk] = *(const bf16x8*)(const void*)(hb + (k0 >> 4) * 1024 + (k0 & 15));
    }
    #pragma unroll
    for (int kk = 0; kk < 16; ++kk) {
      ai = __builtin_amdgcn_mfma_f32_16x16x32_bf16(hfrag[kk], ldb(0, kk + 8), ai, 0, 0, 0);
      ag = __builtin_amdgcn_mfma_f32_16x16x32_bf16(hfrag[kk], ldb(1, kk + 8), ag, 0, 0, 0);
      ao = __builtin_amdgcn_mfma_f32_16x16x32_bf16(hfrag[kk], ldb(2, kk + 8), ao, 0, 0, 0);
    }

    // ---- nonlinearity + write h_{t+1} slice (plain stores into own contiguous block) ----
    unsigned short* hn = hbuf + (size_t)((t + 1) & 1) * (N_B * N_H) + wg * 1024;
    #pragma unroll
    for (int j = 0; j < 4; ++j) {
      float iv = sigm(ai[j] + Bi);
      float gv = tanh_(ag[j] + Bg);
      float ov = sigm(ao[j] + Bo);
      float h = ov * tanh_(iv * gv);
      int row = wave * 16 + q * 4 + j;  // D layout: col=lane&15, row=q*4+j (m89)
      hn[row * 16 + c] = f2bf(h);
    }

    __syncthreads();  // vmcnt(0) drain: all waves' stores are in L2
    if (tid == 0) {
      __builtin_amdgcn_fence(__ATOMIC_RELEASE, "agent");  // wbL2 -> LLC
      __hip_atomic_store(&flags[wg * FLAG_STRIDE], t + 1,
                         __ATOMIC_RELEASE, __HIP_MEMORY_SCOPE_AGENT);
    }
  }

  // ---- epilogue: output = h_T @ W_out + b_out (f32 out); h_T in buffer 0 (T even) ----
  if (wg < 16) {
    if (wave == 0) {
      for (;;) {
        int v = __hip_atomic_load(&flags[(lane & 31) * FLAG_STRIDE],
                                  __ATOMIC_RELAXED, __HIP_MEMORY_SCOPE_AGENT);
        if (__all(v >= T_LEN)) break;
      }
    }
    __syncthreads();
    __builtin_amdgcn_fence(__ATOMIC_ACQUIRE, "agent");

    const unsigned short* hb0 = hbuf + rb * 16;
    f32x4 acc = {0.f, 0.f, 0.f, 0.f};
    #pragma unroll 4
    for (int kk = 0; kk < 16; ++kk) {
      int k0 = kk * 32 + q * 8;
      bf16x8 a = *(const bf16x8*)(const void*)(hb0 + (k0 >> 4) * 1024 + (k0 & 15));
      union { bf16x8 v; unsigned short u[8]; } bb;
      #pragma unroll
      for (int j = 0; j < 8; ++j)
        bb.u[j] = f2bf(Wout[(size_t)(kk * 32 + q * 8 + j) * N_IN + jb + c]);
      acc = __builtin_amdgcn_mfma_f32_16x16x32_bf16(a, bb.v, acc, 0, 0, 0);
    }
    const float Bb = bout[jb + c];
    #pragma unroll
    for (int j = 0; j < 4; ++j) {
      int row = wave * 16 + q * 4 + j;
      out[row * N_IN + jb + c] = acc[j] + Bb;  // f32 store
    }
  }
}

extern "C" void kernel_launch(void* const* d_in, const int* in_sizes, int n_in,
                              void* d_out, int out_size, void* d_ws, size_t ws_size,
                              hipStream_t stream) {
  const float* X    = (const float*)d_in[0];
  const float* HID  = (const float*)d_in[1];
  const float* Wi   = (const float*)d_in[2];
  const float* bi   = (const float*)d_in[3];
  const float* Wg   = (const float*)d_in[4];
  const float* bg   = (const float*)d_in[5];
  const float* Wo   = (const float*)d_in[6];
  const float* bo   = (const float*)d_in[7];
  const float* Wout = (const float*)d_in[8];
  const float* bout = (const float*)d_in[9];

  int* flags = (int*)d_ws;
  unsigned short* hbuf = (unsigned short*)((char*)d_ws + 4096);

  lstm_init<<<dim3(132), dim3(256), 0, stream>>>((int*)d_ws);
  lstm_persist<<<dim3(N_WG), dim3(256), 48 * 768 * 2, stream>>>(
      X, HID, Wi, bi, Wg, bg, Wo, bo, Wout, bout,
      (float*)d_out, hbuf, flags);
}

// Round 10
// 14164.986 us; speedup vs baseline: 1.6439x; 1.1891x over previous
//
#include <hip/hip_runtime.h>
#include <hip/hip_bf16.h>

#define T_LEN 2048
#define N_IN 256
#define N_H 512
#define N_B 64
#define N_WG 32
#define FLAG_STRIDE 32  // ints -> 128B per flag line

typedef float f32x4 __attribute__((ext_vector_type(4)));
typedef __bf16 bf16x8 __attribute__((ext_vector_type(8)));

__device__ __forceinline__ unsigned short f2bf(float f) {
  union { float f; unsigned int i; } x; x.f = f;
  unsigned int r = x.i + 0x7fffu + ((x.i >> 16) & 1u);  // RNE
  return (unsigned short)(r >> 16);
}
__device__ __forceinline__ float sigm(float x) { return 1.0f / (1.0f + __expf(-x)); }
__device__ __forceinline__ float tanh_(float x) {
  float a = fabsf(x);
  float e = __expf(2.0f * a);
  float r = 1.0f - 2.0f / (e + 1.0f);
  return copysignf(r, x);
}
// convert 8 consecutive f32 -> bf16x8 (RNE)
__device__ __forceinline__ bf16x8 cvt8(const float* __restrict__ p) {
  f32x4 a = *(const f32x4*)(const void*)p;
  f32x4 b = *(const f32x4*)(const void*)(p + 4);
  union { bf16x8 v; unsigned short u[8]; } r;
  #pragma unroll
  for (int j = 0; j < 4; ++j) { r.u[j] = f2bf(a[j]); r.u[j + 4] = f2bf(b[j]); }
  return r.v;
}

// ws layout: [0,4096) flags (32 x FLAG_STRIDE ints),
//            [4096, 4096+131072) hbuf: 2 bufs x 32 wg-slices x (64 rows x 16 cols) bf16
__global__ void lstm_init(int* __restrict__ ws) {
  int i = blockIdx.x * 256 + threadIdx.x;  // grid 132 covers 4096B + 128KB
  if (i < (4096 + 2 * N_B * N_H * 2) / 4) ws[i] = 0;
}

__global__ __launch_bounds__(256, 1) void lstm_persist(
    const float* __restrict__ X,     // [64, 2048, 256] f32
    const float* __restrict__ HID,   // [1, 512] f32 (passthrough)
    const float* __restrict__ Wi, const float* __restrict__ bi,
    const float* __restrict__ Wg, const float* __restrict__ bg,
    const float* __restrict__ Wo, const float* __restrict__ bo,
    const float* __restrict__ Wout, const float* __restrict__ bout,
    float* __restrict__ out,                  // f32: [64*256] + [512]
    unsigned short* __restrict__ hbuf,        // see layout above
    int* __restrict__ flags)                  // 32 x FLAG_STRIDE ints
{
  extern __shared__ unsigned short ldsw[];  // weights 73728 B + 2048 B h-transpose scratch
  unsigned short* ldsh = ldsw + 48 * 768;   // [64 rows][16 cols] u16
  const int tid = threadIdx.x;
  const int wg = blockIdx.x;       // 0..31 -> column slice jb..jb+15
  const int lane = tid & 63;
  const int wave = tid >> 6;       // 0..3 -> M-tile (rows 16*wave..)
  const int q = lane >> 4;         // 0..3
  const int c = lane & 15;
  const int jb = wg * 16;

  // hidden passthrough output (independent of recurrence), f32
  if (wg == N_WG - 1) {
    for (int i = tid; i < N_H; i += 256) out[N_B * N_IN + i] = HID[i];
  }

  // ---- stage weight slice into LDS (f32 -> bf16), transposed: Wt[r][k], r = gate*16 + (col-jb) ----
  for (int idx = tid; idx < 48 * 768; idx += 256) {
    int k = idx / 48;
    int r = idx - k * 48;
    int g = r >> 4;
    int cc = r & 15;
    const float* W = (g == 0) ? Wi : ((g == 1) ? Wg : Wo);
    unsigned short v = f2bf(W[k * N_H + jb + cc]);
    int byte = (r * 1536 + k * 2) ^ ((r & 7) << 4);  // XOR swizzle (G4)
    *(unsigned short*)((char*)ldsw + byte) = v;
  }
  __syncthreads();

  // B-fragment read: lane holds Wt[gate*16 + c][kk*32 + q*8 + j], j=0..7 (16B contiguous)
  auto ldb = [&](int g, int kk) -> bf16x8 {
    int r = g * 16 + c;
    int byte = (r * 1536 + kk * 64 + q * 16) ^ ((r & 7) << 4);
    return *(const bf16x8*)((const char*)ldsw + byte);
  };

  const float Bi = bi[jb + c];
  const float Bg = bg[jb + c];
  const float Bo = bo[jb + c];

  const int rb = wave * 16 + c;  // batch row for A-fragments
  const float* xrow = X + (size_t)rb * (T_LEN * N_IN);

  // u64-granular h fragment base for this thread (see layout derivation):
  //   u16 idx of (row rb, col k) = (k>>4)*1024 + rb*16 + (k&15); k = kk*32 + q*8
  //   -> u64 idx = kk*512 + (q>>1)*256 + rb*4 + (q&1)*2
  const int hoff64 = (q >> 1) * 256 + rb * 4 + (q & 1) * 2;

  #pragma unroll 1
  for (int t = 0; t < T_LEN; ++t) {
    f32x4 ai = {0.f, 0.f, 0.f, 0.f};
    f32x4 ag = {0.f, 0.f, 0.f, 0.f};
    f32x4 ao = {0.f, 0.f, 0.f, 0.f};

    // ---- x-part GEMM (independent of h -> before the flag wait) ----
    const float* xp = xrow + (size_t)t * N_IN + q * 8;
    #pragma unroll
    for (int kk = 0; kk < 8; ++kk) {
      bf16x8 a = cvt8(xp + kk * 32);
      ai = __builtin_amdgcn_mfma_f32_16x16x32_bf16(a, ldb(0, kk), ai, 0, 0, 0);
      ag = __builtin_amdgcn_mfma_f32_16x16x32_bf16(a, ldb(1, kk), ag, 0, 0, 0);
      ao = __builtin_amdgcn_mfma_f32_16x16x32_bf16(a, ldb(2, kk), ao, 0, 0, 0);
    }

    // ---- wait until all WGs published h_t (RELAXED sc-polls; no fences needed) ----
    if (wave == 0) {
      for (;;) {
        int v = __hip_atomic_load(&flags[(lane & 31) * FLAG_STRIDE],
                                  __ATOMIC_RELAXED, __HIP_MEMORY_SCOPE_AGENT);
        if (__all(v >= t)) break;
      }
    }
    __syncthreads();

    // ---- h-part GEMM: coherent (sc11) u64 loads, compiler-pipelined ----
    const unsigned long long* hb64 =
        (const unsigned long long*)(hbuf + (size_t)(t & 1) * (N_B * N_H)) + hoff64;
    unsigned long long hreg[32];
    #pragma unroll
    for (int kk = 0; kk < 16; ++kk) {
      hreg[2 * kk]     = __hip_atomic_load(hb64 + kk * 512,     __ATOMIC_RELAXED, __HIP_MEMORY_SCOPE_AGENT);
      hreg[2 * kk + 1] = __hip_atomic_load(hb64 + kk * 512 + 1, __ATOMIC_RELAXED, __HIP_MEMORY_SCOPE_AGENT);
    }
    #pragma unroll
    for (int kk = 0; kk < 16; ++kk) {
      union { unsigned long long u[2]; bf16x8 v; } a;
      a.u[0] = hreg[2 * kk]; a.u[1] = hreg[2 * kk + 1];
      ai = __builtin_amdgcn_mfma_f32_16x16x32_bf16(a.v, ldb(0, kk + 8), ai, 0, 0, 0);
      ag = __builtin_amdgcn_mfma_f32_16x16x32_bf16(a.v, ldb(1, kk + 8), ag, 0, 0, 0);
      ao = __builtin_amdgcn_mfma_f32_16x16x32_bf16(a.v, ldb(2, kk + 8), ao, 0, 0, 0);
    }

    // ---- nonlinearity -> LDS transpose -> coalesced coherent u64 stores ----
    #pragma unroll
    for (int j = 0; j < 4; ++j) {
      float iv = sigm(ai[j] + Bi);
      float gv = tanh_(ag[j] + Bg);
      float ov = sigm(ao[j] + Bo);
      float h = ov * tanh_(iv * gv);
      int row = wave * 16 + q * 4 + j;  // D layout: col=lane&15, row=q*4+j (m89)
      ldsh[row * 16 + c] = f2bf(h);
    }
    __syncthreads();  // LDS visibility across waves
    {
      unsigned long long v = *(const unsigned long long*)(const void*)(ldsh + tid * 4);
      unsigned long long* hn64 =
          (unsigned long long*)(hbuf + (size_t)((t + 1) & 1) * (N_B * N_H) + wg * 1024);
      __hip_atomic_store(&hn64[tid], v, __ATOMIC_RELAXED, __HIP_MEMORY_SCOPE_AGENT);
    }
    __syncthreads();  // vmcnt(0) drain: every thread's sc-store acked at LLC
    if (tid == 0)
      __hip_atomic_store(&flags[wg * FLAG_STRIDE], t + 1,
                         __ATOMIC_RELEASE, __HIP_MEMORY_SCOPE_AGENT);
  }

  // ---- epilogue: output = h_T @ W_out + b_out (f32 out); h_T in buffer 0 (T even) ----
  if (wg < 16) {
    if (wave == 0) {
      for (;;) {
        int v = __hip_atomic_load(&flags[(lane & 31) * FLAG_STRIDE],
                                  __ATOMIC_RELAXED, __HIP_MEMORY_SCOPE_AGENT);
        if (__all(v >= T_LEN)) break;
      }
    }
    __syncthreads();

    const unsigned long long* hb64 = (const unsigned long long*)hbuf + hoff64;
    f32x4 acc = {0.f, 0.f, 0.f, 0.f};
    #pragma unroll 4
    for (int kk = 0; kk < 16; ++kk) {
      union { unsigned long long u[2]; bf16x8 v; } a;
      a.u[0] = __hip_atomic_load(hb64 + kk * 512,     __ATOMIC_RELAXED, __HIP_MEMORY_SCOPE_AGENT);
      a.u[1] = __hip_atomic_load(hb64 + kk * 512 + 1, __ATOMIC_RELAXED, __HIP_MEMORY_SCOPE_AGENT);
      union { bf16x8 v; unsigned short u[8]; } bb;
      #pragma unroll
      for (int j = 0; j < 8; ++j)
        bb.u[j] = f2bf(Wout[(size_t)(kk * 32 + q * 8 + j) * N_IN + jb + c]);
      acc = __builtin_amdgcn_mfma_f32_16x16x32_bf16(a.v, bb.v, acc, 0, 0, 0);
    }
    const float Bb = bout[jb + c];
    #pragma unroll
    for (int j = 0; j < 4; ++j) {
      int row = wave * 16 + q * 4 + j;
      out[row * N_IN + jb + c] = acc[j] + Bb;  // f32 store
    }
  }
}

extern "C" void kernel_launch(void* const* d_in, const int* in_sizes, int n_in,
                              void* d_out, int out_size, void* d_ws, size_t ws_size,
                              hipStream_t stream) {
  const float* X    = (const float*)d_in[0];
  const float* HID  = (const float*)d_in[1];
  const float* Wi   = (const float*)d_in[2];
  const float* bi   = (const float*)d_in[3];
  const float* Wg   = (const float*)d_in[4];
  const float* bg   = (const float*)d_in[5];
  const float* Wo   = (const float*)d_in[6];
  const float* bo   = (const float*)d_in[7];
  const float* Wout = (const float*)d_in[8];
  const float* bout = (const float*)d_in[9];

  int* flags = (int*)d_ws;
  unsigned short* hbuf = (unsigned short*)((char*)d_ws + 4096);

  lstm_init<<<dim3(132), dim3(256), 0, stream>>>((int*)d_ws);
  lstm_persist<<<dim3(N_WG), dim3(256), 48 * 768 * 2 + 2048, stream>>>(
      X, HID, Wi, bi, Wg, bg, Wo, bo, Wout, bout,
      (float*)d_out, hbuf, flags);
}

// Round 11
// 9243.844 us; speedup vs baseline: 2.5190x; 1.5324x over previous
//
#include <hip/hip_runtime.h>
#include <hip/hip_bf16.h>

#define T_LEN 2048
#define N_IN 256
#define N_H 512
#define N_B 64
#define FLAG_STRIDE 32  // ints -> 128B per flag line

typedef float f32x4 __attribute__((ext_vector_type(4)));
typedef __bf16 bf16x8 __attribute__((ext_vector_type(8)));

__device__ __forceinline__ unsigned short f2bf(float f) {
  union { float f; unsigned int i; } x; x.f = f;
  unsigned int r = x.i + 0x7fffu + ((x.i >> 16) & 1u);  // RNE
  return (unsigned short)(r >> 16);
}
__device__ __forceinline__ float sigm(float x) { return 1.0f / (1.0f + __expf(-x)); }
__device__ __forceinline__ float tanh_(float x) {
  float a = fabsf(x);
  float e = __expf(2.0f * a);
  float r = 1.0f - 2.0f / (e + 1.0f);
  return copysignf(r, x);
}
// convert 8 consecutive f32 -> bf16x8 (RNE)
__device__ __forceinline__ bf16x8 cvt8(const float* __restrict__ p) {
  f32x4 a = *(const f32x4*)(const void*)p;
  f32x4 b = *(const f32x4*)(const void*)(p + 4);
  union { bf16x8 v; unsigned short u[8]; } r;
  #pragma unroll
  for (int j = 0; j < 4; ++j) { r.u[j] = f2bf(a[j]); r.u[j + 4] = f2bf(b[j]); }
  return r.v;
}

// ws layout: [0, 8192) flags (64 x FLAG_STRIDE ints)
//            [8192, 8192+131072) hbuf u16: [group 4][buf 2][producer 16][row 16][col 32]
__global__ void lstm_init(int* __restrict__ ws) {
  int i = blockIdx.x * 256 + threadIdx.x;  // grid 136 covers 8192B + 128KB
  if (i < (8192 + 2 * N_B * N_H * 2) / 4) ws[i] = 0;
}

// 64 WGs x 128 threads. Group g = blockIdx&3 owns batch rows 16g..16g+15 (independent
// recurrence domain). Member m = blockIdx>>2 owns hidden cols 32m..32m+31 (3 gates in LDS).
__global__ __launch_bounds__(128, 1) void lstm_persist(
    const float* __restrict__ X,     // [64, 2048, 256] f32
    const float* __restrict__ HID,   // [1, 512] f32 (passthrough)
    const float* __restrict__ Wi, const float* __restrict__ bi,
    const float* __restrict__ Wg, const float* __restrict__ bg,
    const float* __restrict__ Wo, const float* __restrict__ bo,
    const float* __restrict__ Wout, const float* __restrict__ bout,
    float* __restrict__ out,                  // f32: [64*256] + [512]
    unsigned short* __restrict__ hbuf,        // see layout above
    int* __restrict__ flags)                  // 64 x FLAG_STRIDE ints
{
  extern __shared__ unsigned short ldsw[];  // 96 rows x 768 k swizzled (147456 B) + 1024 B scratch
  unsigned short* ldsh = ldsw + 96 * 768;   // [16 rows][32 cols] u16
  const int tid = threadIdx.x;
  const int b = blockIdx.x;
  const int g = b & 3;             // group (batch split)
  const int m = b >> 2;            // member: hidden col slice
  const int lane = tid & 63;
  const int wave = tid >> 6;       // 0..1 -> col-tile within WG
  const int q = lane >> 4;         // 0..3
  const int c = lane & 15;
  const int jb = m * 32;           // WG's hidden col base
  const int wcol = wave * 16;      // col-tile offset within WG

  // hidden passthrough output (independent of recurrence), f32
  if (b == 0) {
    for (int i = tid; i < N_H; i += 128) out[N_B * N_IN + i] = HID[i];
  }

  // ---- stage weight slice into LDS (f32 -> bf16), transposed: Wt[r][k], r = gate*32 + (col-jb) ----
  for (int idx = tid; idx < 96 * 768; idx += 128) {
    int k = idx / 96;
    int r = idx - k * 96;
    int g3 = r >> 5;
    int cc = r & 31;
    const float* W = (g3 == 0) ? Wi : ((g3 == 1) ? Wg : Wo);
    unsigned short v = f2bf(W[k * N_H + jb + cc]);
    int byte = (r * 1536 + k * 2) ^ ((r & 7) << 4);  // XOR swizzle (G4)
    *(unsigned short*)((char*)ldsw + byte) = v;
  }
  __syncthreads();

  // B-fragment read: lane holds Wt[gg*32 + wcol + c][kt*32 + q*8 + j], j=0..7 (16B contiguous)
  auto ldb = [&](int gg, int kt) -> bf16x8 {
    int r = gg * 32 + wcol + c;
    int byte = (r * 1536 + kt * 64 + q * 16) ^ ((r & 7) << 4);
    return *(const bf16x8*)((const char*)ldsw + byte);
  };

  const float Bi = bi[jb + wcol + c];
  const float Bg = bg[jb + wcol + c];
  const float Bo = bo[jb + wcol + c];

  const float* xrow = X + (size_t)(g * 16 + c) * (T_LEN * N_IN);  // A row c = group row c

  // group h buffers (u16 units): base = g*16384 + buf*8192; slice layout [kkprod][row][col32]
  unsigned short* gh0 = hbuf + g * 16384;
  // read fragment (kk, row c, kslot q): u64 idx = kk*128 + c*8 + q*2 (+0,+1)
  const int roff64 = c * 8 + q * 2;

  #pragma unroll 1
  for (int t = 0; t < T_LEN; ++t) {
    f32x4 ai = {0.f, 0.f, 0.f, 0.f};
    f32x4 ag = {0.f, 0.f, 0.f, 0.f};
    f32x4 ao = {0.f, 0.f, 0.f, 0.f};

    // ---- x-part GEMM (independent of h -> before the flag wait) ----
    const float* xp = xrow + (size_t)t * N_IN + q * 8;
    #pragma unroll
    for (int kk = 0; kk < 8; ++kk) {
      bf16x8 a = cvt8(xp + kk * 32);
      ai = __builtin_amdgcn_mfma_f32_16x16x32_bf16(a, ldb(0, kk), ai, 0, 0, 0);
      ag = __builtin_amdgcn_mfma_f32_16x16x32_bf16(a, ldb(1, kk), ag, 0, 0, 0);
      ao = __builtin_amdgcn_mfma_f32_16x16x32_bf16(a, ldb(2, kk), ao, 0, 0, 0);
    }

    // ---- wait until this group's 16 producers published h_t ----
    if (wave == 0) {
      for (;;) {
        int v = __hip_atomic_load(&flags[(g * 16 + (lane & 15)) * FLAG_STRIDE],
                                  __ATOMIC_RELAXED, __HIP_MEMORY_SCOPE_AGENT);
        if (__all(v >= t)) break;
      }
    }
    __syncthreads();

    // ---- h-part GEMM: coherent (sc) u64 loads of the group's 16KB h tile ----
    const unsigned long long* hb64 =
        (const unsigned long long*)(gh0 + (size_t)(t & 1) * 8192) + roff64;
    unsigned long long hreg[32];
    #pragma unroll
    for (int kk = 0; kk < 16; ++kk) {
      hreg[2 * kk]     = __hip_atomic_load(hb64 + kk * 128,     __ATOMIC_RELAXED, __HIP_MEMORY_SCOPE_AGENT);
      hreg[2 * kk + 1] = __hip_atomic_load(hb64 + kk * 128 + 1, __ATOMIC_RELAXED, __HIP_MEMORY_SCOPE_AGENT);
    }
    #pragma unroll
    for (int kk = 0; kk < 16; ++kk) {
      union { unsigned long long u[2]; bf16x8 v; } a;
      a.u[0] = hreg[2 * kk]; a.u[1] = hreg[2 * kk + 1];
      ai = __builtin_amdgcn_mfma_f32_16x16x32_bf16(a.v, ldb(0, kk + 8), ai, 0, 0, 0);
      ag = __builtin_amdgcn_mfma_f32_16x16x32_bf16(a.v, ldb(1, kk + 8), ag, 0, 0, 0);
      ao = __builtin_amdgcn_mfma_f32_16x16x32_bf16(a.v, ldb(2, kk + 8), ao, 0, 0, 0);
    }

    // ---- nonlinearity -> LDS transpose -> coalesced coherent u64 stores ----
    #pragma unroll
    for (int j = 0; j < 4; ++j) {
      float iv = sigm(ai[j] + Bi);
      float gv = tanh_(ag[j] + Bg);
      float ov = sigm(ao[j] + Bo);
      float h = ov * tanh_(iv * gv);
      int row = q * 4 + j;  // D layout: col=lane&15, row=q*4+j (m89)
      ldsh[row * 32 + wcol + c] = f2bf(h);
    }
    __syncthreads();  // LDS visibility across both waves
    {
      unsigned long long v = *(const unsigned long long*)(const void*)(ldsh + tid * 4);
      unsigned long long* hn64 =
          (unsigned long long*)(gh0 + (size_t)((t + 1) & 1) * 8192 + m * 512);
      __hip_atomic_store(&hn64[tid], v, __ATOMIC_RELAXED, __HIP_MEMORY_SCOPE_AGENT);
    }
    __syncthreads();  // vmcnt(0) drain: every thread's sc-store acked
    if (tid == 0)
      __hip_atomic_store(&flags[(g * 16 + m) * FLAG_STRIDE], t + 1,
                         __ATOMIC_RELEASE, __HIP_MEMORY_SCOPE_AGENT);
  }

  // ---- epilogue: out[group rows][16 cols] = h_T @ W_out + b_out ; h_T in buf 0 (T even) ----
  {
    if (wave == 0) {
      for (;;) {
        int v = __hip_atomic_load(&flags[(g * 16 + (lane & 15)) * FLAG_STRIDE],
                                  __ATOMIC_RELAXED, __HIP_MEMORY_SCOPE_AGENT);
        if (__all(v >= T_LEN)) break;
      }
    }
    __syncthreads();

    if (wave == 0) {
      const unsigned long long* hb64 = (const unsigned long long*)gh0 + roff64;
      f32x4 acc = {0.f, 0.f, 0.f, 0.f};
      #pragma unroll 4
      for (int kk = 0; kk < 16; ++kk) {
        union { unsigned long long u[2]; bf16x8 v; } a;
        a.u[0] = __hip_atomic_load(hb64 + kk * 128,     __ATOMIC_RELAXED, __HIP_MEMORY_SCOPE_AGENT);
        a.u[1] = __hip_atomic_load(hb64 + kk * 128 + 1, __ATOMIC_RELAXED, __HIP_MEMORY_SCOPE_AGENT);
        union { bf16x8 v; unsigned short u[8]; } bb;
        #pragma unroll
        for (int j = 0; j < 8; ++j)
          bb.u[j] = f2bf(Wout[(size_t)(kk * 32 + q * 8 + j) * N_IN + m * 16 + c]);
        acc = __builtin_amdgcn_mfma_f32_16x16x32_bf16(a.v, bb.v, acc, 0, 0, 0);
      }
      const float Bb = bout[m * 16 + c];
      #pragma unroll
      for (int j = 0; j < 4; ++j) {
        int row = q * 4 + j;  // group row
        out[(g * 16 + row) * N_IN + m * 16 + c] = acc[j] + Bb;  // f32 store
      }
    }
  }
}

extern "C" void kernel_launch(void* const* d_in, const int* in_sizes, int n_in,
                              void* d_out, int out_size, void* d_ws, size_t ws_size,
                              hipStream_t stream) {
  const float* X    = (const float*)d_in[0];
  const float* HID  = (const float*)d_in[1];
  const float* Wi   = (const float*)d_in[2];
  const float* bi   = (const float*)d_in[3];
  const float* Wg   = (const float*)d_in[4];
  const float* bg   = (const float*)d_in[5];
  const float* Wo   = (const float*)d_in[6];
  const float* bo   = (const float*)d_in[7];
  const float* Wout = (const float*)d_in[8];
  const float* bout = (const float*)d_in[9];

  int* flags = (int*)d_ws;
  unsigned short* hbuf = (unsigned short*)((char*)d_ws + 8192);

  lstm_init<<<dim3(136), dim3(256), 0, stream>>>((int*)d_ws);
  lstm_persist<<<dim3(64), dim3(128), 96 * 768 * 2 + 1024, stream>>>(
      X, HID, Wi, bi, Wg, bg, Wo, bo, Wout, bout,
      (float*)d_out, hbuf, flags);
}